// Round 2
// baseline (343.471 us; speedup 1.0000x reference)
//
#include <hip/hip_runtime.h>

#define B_ 32
#define C_ 64
#define H_ 128
#define W_ 128
#define HW_ (H_*W_)
#define CHW_ (C_*HW_)

// ---------------------------------------------------------------------------
// k1: per-pixel channel mean & max over C=64, plus per-batch pooled sums.
// One thread = 4 consecutive pixels (float4). Block = 256 thr = 1024 pixels,
// always within one batch (HW=16384 divisible by 1024).
// ---------------------------------------------------------------------------
__global__ __launch_bounds__(256) void k1_reduce(
    const float* __restrict__ x, float* __restrict__ avgmap,
    float* __restrict__ maxmap, float* __restrict__ bsum)
{
    int t = blockIdx.x * 256 + threadIdx.x;
    int base = t * 4;
    int b = base >> 14;            // / HW_
    int q = base & (HW_ - 1);
    const float4* xp = (const float4*)(x + (size_t)b * CHW_ + q);
    float4 v = xp[0];
    float4 s = v, m = v;
    #pragma unroll 8
    for (int c = 1; c < C_; ++c) {
        float4 u = xp[c * (HW_ / 4)];
        s.x += u.x; s.y += u.y; s.z += u.z; s.w += u.w;
        m.x = fmaxf(m.x, u.x); m.y = fmaxf(m.y, u.y);
        m.z = fmaxf(m.z, u.z); m.w = fmaxf(m.w, u.w);
    }
    const float inv = 1.0f / C_;
    float4 a = make_float4(s.x * inv, s.y * inv, s.z * inv, s.w * inv);
    ((float4*)avgmap)[t] = a;
    ((float4*)maxmap)[t] = m;

    // block reduction of pooled sums (sum of avg vals, sum of max vals)
    float la = a.x + a.y + a.z + a.w;
    float lm = m.x + m.y + m.z + m.w;
    #pragma unroll
    for (int o = 32; o > 0; o >>= 1) {
        la += __shfl_down(la, o);
        lm += __shfl_down(lm, o);
    }
    __shared__ float wa[4], wm[4];
    int lane = threadIdx.x & 63, wid = threadIdx.x >> 6;
    if (lane == 0) { wa[wid] = la; wm[wid] = lm; }
    __syncthreads();
    if (threadIdx.x == 0) {
        atomicAdd(&bsum[2 * b],     wa[0] + wa[1] + wa[2] + wa[3]);
        atomicAdd(&bsum[2 * b + 1], wm[0] + wm[1] + wm[2] + wm[3]);
    }
}

// ---------------------------------------------------------------------------
// k2: router MLP 4->8->3 + softmax, one thread per batch.
// pooled = [mean(avg), mean(max), 0, 0]  (xg/yg pool to exactly 0)
// ---------------------------------------------------------------------------
__global__ void k2_router(const float* __restrict__ bsum,
                          const float* __restrict__ rw1, const float* __restrict__ rb1,
                          const float* __restrict__ rw2, const float* __restrict__ rb2,
                          float* __restrict__ rwout)
{
    int b = threadIdx.x;
    if (b >= B_) return;
    float p0 = bsum[2 * b]     * (1.0f / HW_);
    float p1 = bsum[2 * b + 1] * (1.0f / HW_);
    float hid[8];
    #pragma unroll
    for (int j = 0; j < 8; ++j)
        hid[j] = fmaxf(0.0f, rb1[j] + rw1[j * 4] * p0 + rw1[j * 4 + 1] * p1);
    float lg[3];
    #pragma unroll
    for (int i = 0; i < 3; ++i) {
        float acc = rb2[i];
        #pragma unroll
        for (int j = 0; j < 8; ++j) acc += hid[j] * rw2[i * 8 + j];
        lg[i] = acc;
    }
    float mx = fmaxf(lg[0], fmaxf(lg[1], lg[2]));
    float e0 = expf(lg[0] - mx), e1 = expf(lg[1] - mx), e2 = expf(lg[2] - mx);
    float inv = 1.0f / (e0 + e1 + e2);
    rwout[b * 3 + 0] = e0 * inv;
    rwout[b * 3 + 1] = e1 * inv;
    rwout[b * 3 + 2] = e2 * inv;
}

// ---------------------------------------------------------------------------
// k3: 3 depthwise convs (k3d1, k7d1, k7d2) + pointwise fold + router combine
// + sigmoid -> sa. 16x16 output tile per block, halo 6, avg/max in LDS.
// Row stride 40 ( ≡ 8 mod 32 ) -> uniform 2-way bank aliasing (free).
// xg/yg channels computed analytically with zero-pad masks.
// ---------------------------------------------------------------------------
__global__ __launch_bounds__(256) void k3_branches(
    const float* __restrict__ avgmap, const float* __restrict__ maxmap,
    const float* __restrict__ dw0, const float* __restrict__ dw1,
    const float* __restrict__ dw2,
    const float* __restrict__ pw0w, const float* __restrict__ pw0b,
    const float* __restrict__ pw1w, const float* __restrict__ pw1b,
    const float* __restrict__ pw2w, const float* __restrict__ pw2b,
    const float* __restrict__ rw, const float* __restrict__ t_raw,
    float* __restrict__ sa_out)
{
    __shared__ float sA[28][40];
    __shared__ float sM[28][40];
    __shared__ float wf0[36], wf1[196], wf2[196];

    int b = blockIdx.z;
    int tix = threadIdx.y * 16 + threadIdx.x;
    int gx0 = blockIdx.x * 16, gy0 = blockIdx.y * 16;
    const float* am = avgmap + (size_t)b * HW_;
    const float* mm = maxmap + (size_t)b * HW_;

    for (int idx = tix; idx < 28 * 28; idx += 256) {
        int r = idx / 28, c = idx % 28;
        int gy = gy0 - 6 + r, gx = gx0 - 6 + c;
        bool ok = ((unsigned)gy < H_) && ((unsigned)gx < W_);
        sA[r][c] = ok ? am[gy * W_ + gx] : 0.0f;
        sM[r][c] = ok ? mm[gy * W_ + gx] : 0.0f;
    }
    if (tix < 36)  wf0[tix] = pw0w[tix / 9]  * dw0[tix];
    if (tix < 196) {
        wf1[tix] = pw1w[tix / 49] * dw1[tix];
        wf2[tix] = pw2w[tix / 49] * dw2[tix];   // FIX: full 196 loaded (was 60)
    }
    __syncthreads();

    int lx = threadIdx.x, ly = threadIdx.y;
    int gx = gx0 + lx, gy = gy0 + ly;
    const float sc = 2.0f / 127.0f;

    float z0 = pw0b[0], z1 = pw1b[0], z2 = pw2b[0];

    // branch 0: k=3 d=1
    #pragma unroll
    for (int ky = 0; ky < 3; ++ky) {
        #pragma unroll
        for (int kx = 0; kx < 3; ++kx) {
            int i = ky - 1, j = kx - 1;
            float a = sA[ly + 6 + i][lx + 6 + j];
            float m = sM[ly + 6 + i][lx + 6 + j];
            int iy = gy + i, ix = gx + j;
            bool ok = ((unsigned)iy < H_) && ((unsigned)ix < W_);
            float xv = ok ? (ix * sc - 1.0f) : 0.0f;
            float yv = ok ? (iy * sc - 1.0f) : 0.0f;
            int t = ky * 3 + kx;
            z0 += wf0[t] * a + wf0[9 + t] * m + wf0[18 + t] * xv + wf0[27 + t] * yv;
        }
    }
    // branch 1: k=7 d=1
    #pragma unroll
    for (int ky = 0; ky < 7; ++ky) {
        #pragma unroll
        for (int kx = 0; kx < 7; ++kx) {
            int i = ky - 3, j = kx - 3;
            float a = sA[ly + 6 + i][lx + 6 + j];
            float m = sM[ly + 6 + i][lx + 6 + j];
            int iy = gy + i, ix = gx + j;
            bool ok = ((unsigned)iy < H_) && ((unsigned)ix < W_);
            float xv = ok ? (ix * sc - 1.0f) : 0.0f;
            float yv = ok ? (iy * sc - 1.0f) : 0.0f;
            int t = ky * 7 + kx;
            z1 += wf1[t] * a + wf1[49 + t] * m + wf1[98 + t] * xv + wf1[147 + t] * yv;
        }
    }
    // branch 2: k=7 d=2
    #pragma unroll
    for (int ky = 0; ky < 7; ++ky) {
        #pragma unroll
        for (int kx = 0; kx < 7; ++kx) {
            int i = (ky - 3) * 2, j = (kx - 3) * 2;
            float a = sA[ly + 6 + i][lx + 6 + j];
            float m = sM[ly + 6 + i][lx + 6 + j];
            int iy = gy + i, ix = gx + j;
            bool ok = ((unsigned)iy < H_) && ((unsigned)ix < W_);
            float xv = ok ? (ix * sc - 1.0f) : 0.0f;
            float yv = ok ? (iy * sc - 1.0f) : 0.0f;
            int t = ky * 7 + kx;
            z2 += wf2[t] * a + wf2[49 + t] * m + wf2[98 + t] * xv + wf2[147 + t] * yv;
        }
    }

    float wl = rw[b * 3] * z0 + rw[b * 3 + 1] * z1 + rw[b * 3 + 2] * z2;
    float T = log1pf(expf(t_raw[0])) + 1e-6f;
    float s = 1.0f / (1.0f + expf(-wl / T));
    sa_out[(size_t)b * HW_ + gy * W_ + gx] = s;
}

// ---------------------------------------------------------------------------
// k4: Y = x * sa (broadcast over channels), float4 per thread.
// ---------------------------------------------------------------------------
__global__ __launch_bounds__(256) void k4_mul(
    const float* __restrict__ x, const float* __restrict__ sa,
    float* __restrict__ y)
{
    size_t t = (size_t)blockIdx.x * 256 + threadIdx.x;
    size_t base = t * 4;
    int b = (int)(base >> 20);          // / (C*HW)
    int q = (int)(base & (HW_ - 1));    // pixel offset within plane
    float4 xv = ((const float4*)x)[t];
    float4 sv = *(const float4*)(sa + (size_t)b * HW_ + q);
    float4 yv = make_float4(xv.x * sv.x, xv.y * sv.y, xv.z * sv.z, xv.w * sv.w);
    ((float4*)y)[t] = yv;
}

extern "C" void kernel_launch(void* const* d_in, const int* in_sizes, int n_in,
                              void* d_out, int out_size, void* d_ws, size_t ws_size,
                              hipStream_t stream)
{
    const float* x     = (const float*)d_in[0];
    const float* dw0   = (const float*)d_in[1];
    const float* dw1   = (const float*)d_in[2];
    const float* dw2   = (const float*)d_in[3];
    const float* pw0w  = (const float*)d_in[4];
    const float* pw0b  = (const float*)d_in[5];
    const float* pw1w  = (const float*)d_in[6];
    const float* pw1b  = (const float*)d_in[7];
    const float* pw2w  = (const float*)d_in[8];
    const float* pw2b  = (const float*)d_in[9];
    const float* rw1   = (const float*)d_in[10];
    const float* rb1   = (const float*)d_in[11];
    const float* rw2   = (const float*)d_in[12];
    const float* rb2   = (const float*)d_in[13];
    const float* t_raw = (const float*)d_in[14];

    float* ws     = (float*)d_ws;
    float* avgmap = ws;                       // 524288 floats
    float* maxmap = ws + 524288;              // 524288 floats
    float* bsum   = ws + 1048576;             // 64 floats
    float* rw     = ws + 1048640;             // 96 floats

    float* Y  = (float*)d_out;
    float* sa = Y + (size_t)B_ * CHW_;        // 524288 floats

    hipMemsetAsync(bsum, 0, 64 * sizeof(float), stream);

    k1_reduce<<<B_ * HW_ / 4 / 256, 256, 0, stream>>>(x, avgmap, maxmap, bsum);
    k2_router<<<1, 64, 0, stream>>>(bsum, rw1, rb1, rw2, rb2, rw);

    dim3 g3(W_ / 16, H_ / 16, B_), b3(16, 16);
    k3_branches<<<g3, b3, 0, stream>>>(avgmap, maxmap, dw0, dw1, dw2,
                                       pw0w, pw0b, pw1w, pw1b, pw2w, pw2b,
                                       rw, t_raw, sa);

    k4_mul<<<B_ * CHW_ / 4 / 256, 256, 0, stream>>>(x, sa, Y);
}

// Round 3
// 307.858 us; speedup vs baseline: 1.1157x; 1.1157x over previous
//
#include <hip/hip_runtime.h>

#define B_ 32
#define C_ 64
#define H_ 128
#define W_ 128
#define HW_ (H_*W_)
#define CHW_ (C_*HW_)

// ---------------------------------------------------------------------------
// k1: per-pixel channel mean & max over C=64, plus per-block pooled partial
// sums (no atomics, no memset needed). One thread = 4 consecutive pixels
// (float4). Block = 256 thr = 1024 pixels, always within one batch
// (HW=16384 divisible by 1024 -> 16 blocks per batch).
// ---------------------------------------------------------------------------
__global__ __launch_bounds__(256) void k1_reduce(
    const float* __restrict__ x, float* __restrict__ avgmap,
    float* __restrict__ maxmap, float* __restrict__ partial)
{
    int t = blockIdx.x * 256 + threadIdx.x;
    int base = t * 4;
    int b = base >> 14;            // / HW_
    int q = base & (HW_ - 1);
    const float4* xp = (const float4*)(x + (size_t)b * CHW_ + q);
    float4 v = xp[0];
    float4 s = v, m = v;
    #pragma unroll 8
    for (int c = 1; c < C_; ++c) {
        float4 u = xp[c * (HW_ / 4)];
        s.x += u.x; s.y += u.y; s.z += u.z; s.w += u.w;
        m.x = fmaxf(m.x, u.x); m.y = fmaxf(m.y, u.y);
        m.z = fmaxf(m.z, u.z); m.w = fmaxf(m.w, u.w);
    }
    const float inv = 1.0f / C_;
    float4 a = make_float4(s.x * inv, s.y * inv, s.z * inv, s.w * inv);
    ((float4*)avgmap)[t] = a;
    ((float4*)maxmap)[t] = m;

    // block reduction of pooled sums (sum of avg vals, sum of max vals)
    float la = a.x + a.y + a.z + a.w;
    float lm = m.x + m.y + m.z + m.w;
    #pragma unroll
    for (int o = 32; o > 0; o >>= 1) {
        la += __shfl_down(la, o);
        lm += __shfl_down(lm, o);
    }
    __shared__ float wa[4], wm[4];
    int lane = threadIdx.x & 63, wid = threadIdx.x >> 6;
    if (lane == 0) { wa[wid] = la; wm[wid] = lm; }
    __syncthreads();
    if (threadIdx.x == 0) {
        partial[2 * blockIdx.x]     = wa[0] + wa[1] + wa[2] + wa[3];
        partial[2 * blockIdx.x + 1] = wm[0] + wm[1] + wm[2] + wm[3];
    }
}

// ---------------------------------------------------------------------------
// k2: sum 16 partials per batch, then router MLP 4->8->3 + softmax.
// pooled = [mean(avg), mean(max), 0, 0]  (xg/yg pool to exactly 0)
// ---------------------------------------------------------------------------
__global__ void k2_router(const float* __restrict__ partial,
                          const float* __restrict__ rw1, const float* __restrict__ rb1,
                          const float* __restrict__ rw2, const float* __restrict__ rb2,
                          float* __restrict__ rwout)
{
    int b = threadIdx.x;
    if (b >= B_) return;
    float s0 = 0.0f, s1 = 0.0f;
    #pragma unroll
    for (int i = 0; i < 16; ++i) {
        s0 += partial[2 * (b * 16 + i)];
        s1 += partial[2 * (b * 16 + i) + 1];
    }
    float p0 = s0 * (1.0f / HW_);
    float p1 = s1 * (1.0f / HW_);
    float hid[8];
    #pragma unroll
    for (int j = 0; j < 8; ++j)
        hid[j] = fmaxf(0.0f, rb1[j] + rw1[j * 4] * p0 + rw1[j * 4 + 1] * p1);
    float lg[3];
    #pragma unroll
    for (int i = 0; i < 3; ++i) {
        float acc = rb2[i];
        #pragma unroll
        for (int j = 0; j < 8; ++j) acc += hid[j] * rw2[i * 8 + j];
        lg[i] = acc;
    }
    float mx = fmaxf(lg[0], fmaxf(lg[1], lg[2]));
    float e0 = expf(lg[0] - mx), e1 = expf(lg[1] - mx), e2 = expf(lg[2] - mx);
    float inv = 1.0f / (e0 + e1 + e2);
    rwout[b * 3 + 0] = e0 * inv;
    rwout[b * 3 + 1] = e1 * inv;
    rwout[b * 3 + 2] = e2 * inv;
}

// ---------------------------------------------------------------------------
// k34: fused branches + combine + sigmoid + Y = x*sa.
// Block = 2 full image rows (128x2 tile). LDS holds 14 rows x 140 cols of
// avg/max (±6-row halo, 6 zero-pad cols each side -> conv zero-padding is
// free). After computing sa into LDS, 4 waves apply it over 64 channels:
// per channel the tile is 1 KiB contiguous; wave w takes channels w,w+4,...
// with lane-striped float4 -> 1 KiB per memory instruction.
// ---------------------------------------------------------------------------
__global__ __launch_bounds__(256) void k34_branches_apply(
    const float* __restrict__ x,
    const float* __restrict__ avgmap, const float* __restrict__ maxmap,
    const float* __restrict__ dw0, const float* __restrict__ dw1,
    const float* __restrict__ dw2,
    const float* __restrict__ pw0w, const float* __restrict__ pw0b,
    const float* __restrict__ pw1w, const float* __restrict__ pw1b,
    const float* __restrict__ pw2w, const float* __restrict__ pw2b,
    const float* __restrict__ rw, const float* __restrict__ t_raw,
    float* __restrict__ y, float* __restrict__ sa_out)
{
    __shared__ float sA[14][140];
    __shared__ float sM[14][140];
    __shared__ float wf0[36], wf1[196], wf2[196];
    __shared__ float ssa[256];

    int b  = blockIdx.y;
    int y0 = blockIdx.x * 2;               // first of 2 output rows
    int tix = threadIdx.x;
    const float* am = avgmap + (size_t)b * HW_;
    const float* mm = maxmap + (size_t)b * HW_;

    // stage 14 rows x 128 cols of each map (float4), rows y0-6 .. y0+7
    for (int idx = tix; idx < 14 * 32; idx += 256) {
        int r = idx >> 5, c4 = idx & 31;
        int gy = y0 - 6 + r;
        bool ok = (unsigned)gy < H_;
        float4 av = ok ? ((const float4*)(am + gy * W_))[c4]
                       : make_float4(0.f, 0.f, 0.f, 0.f);
        float4 mv = ok ? ((const float4*)(mm + gy * W_))[c4]
                       : make_float4(0.f, 0.f, 0.f, 0.f);
        float* pa = &sA[r][6 + c4 * 4];
        float* pm = &sM[r][6 + c4 * 4];
        pa[0] = av.x; pa[1] = av.y; pa[2] = av.z; pa[3] = av.w;
        pm[0] = mv.x; pm[1] = mv.y; pm[2] = mv.z; pm[3] = mv.w;
    }
    // zero pad columns (6 each side, 14 rows): 14*12 = 168 entries per map
    for (int idx = tix; idx < 14 * 12; idx += 256) {
        int r = idx / 12, c = idx % 12;
        int cc = (c < 6) ? c : (134 + c - 6);
        sA[r][cc] = 0.0f;
        sM[r][cc] = 0.0f;
    }
    // folded weights: wf[ch*K2 + tap] = pw[ch] * dw[ch][tap]
    if (tix < 36)  wf0[tix] = pw0w[tix / 9]  * dw0[tix];
    if (tix < 196) {
        wf1[tix] = pw1w[tix / 49] * dw1[tix];
        wf2[tix] = pw2w[tix / 49] * dw2[tix];
    }
    __syncthreads();

    int ly = tix >> 7;                     // 0..1
    int lx = tix & 127;                    // 0..127
    int gy = y0 + ly;
    const float sc = 2.0f / 127.0f;
    const float xv_c = lx * sc - 1.0f;     // this column's xg (always in-bounds)

    float z0 = pw0b[0], z1 = pw1b[0], z2 = pw2b[0];

    // branch 0: k=3 d=1
    #pragma unroll
    for (int ky = 0; ky < 3; ++ky) {
        #pragma unroll
        for (int kx = 0; kx < 3; ++kx) {
            int i = ky - 1, j = kx - 1;
            float a = sA[ly + 6 + i][lx + 6 + j];
            float m = sM[ly + 6 + i][lx + 6 + j];
            int iy = gy + i, ix = lx + j;
            bool ok = ((unsigned)iy < H_) && ((unsigned)ix < W_);
            float xv = ok ? (ix * sc - 1.0f) : 0.0f;
            float yv = ok ? (iy * sc - 1.0f) : 0.0f;
            int t = ky * 3 + kx;
            z0 += wf0[t] * a + wf0[9 + t] * m + wf0[18 + t] * xv + wf0[27 + t] * yv;
        }
    }
    // branch 1: k=7 d=1
    #pragma unroll
    for (int ky = 0; ky < 7; ++ky) {
        #pragma unroll
        for (int kx = 0; kx < 7; ++kx) {
            int i = ky - 3, j = kx - 3;
            float a = sA[ly + 6 + i][lx + 6 + j];
            float m = sM[ly + 6 + i][lx + 6 + j];
            int iy = gy + i, ix = lx + j;
            bool ok = ((unsigned)iy < H_) && ((unsigned)ix < W_);
            float xv = ok ? (ix * sc - 1.0f) : 0.0f;
            float yv = ok ? (iy * sc - 1.0f) : 0.0f;
            int t = ky * 7 + kx;
            z1 += wf1[t] * a + wf1[49 + t] * m + wf1[98 + t] * xv + wf1[147 + t] * yv;
        }
    }
    // branch 2: k=7 d=2
    #pragma unroll
    for (int ky = 0; ky < 7; ++ky) {
        #pragma unroll
        for (int kx = 0; kx < 7; ++kx) {
            int i = (ky - 3) * 2, j = (kx - 3) * 2;
            float a = sA[ly + 6 + i][lx + 6 + j];
            float m = sM[ly + 6 + i][lx + 6 + j];
            int iy = gy + i, ix = lx + j;
            bool ok = ((unsigned)iy < H_) && ((unsigned)ix < W_);
            float xv = ok ? (ix * sc - 1.0f) : 0.0f;
            float yv = ok ? (iy * sc - 1.0f) : 0.0f;
            int t = ky * 7 + kx;
            z2 += wf2[t] * a + wf2[49 + t] * m + wf2[98 + t] * xv + wf2[147 + t] * yv;
        }
    }

    float wl = rw[b * 3] * z0 + rw[b * 3 + 1] * z1 + rw[b * 3 + 2] * z2;
    float T = log1pf(expf(t_raw[0])) + 1e-6f;
    float s = 1.0f / (1.0f + expf(-wl / T));
    ssa[tix] = s;
    sa_out[(size_t)b * HW_ + gy * W_ + lx] = s;
    __syncthreads();

    // apply: per channel the 256-pixel tile is one contiguous 1 KiB chunk.
    // wave w handles channels w, w+4, ..., lane l the float4 at l*4.
    int wid  = tix >> 6;                   // 0..3
    int lane = tix & 63;                   // 0..63
    float4 sv = ((const float4*)ssa)[lane];
    const float* xt = x + (size_t)b * CHW_ + y0 * W_;
    float*       yt = y + (size_t)b * CHW_ + y0 * W_;
    #pragma unroll 4
    for (int k = 0; k < 16; ++k) {
        int c = wid + k * 4;
        float4 xv4 = ((const float4*)(xt + c * HW_))[lane];
        float4 yv4 = make_float4(xv4.x * sv.x, xv4.y * sv.y,
                                 xv4.z * sv.z, xv4.w * sv.w);
        ((float4*)(yt + c * HW_))[lane] = yv4;
    }
}

extern "C" void kernel_launch(void* const* d_in, const int* in_sizes, int n_in,
                              void* d_out, int out_size, void* d_ws, size_t ws_size,
                              hipStream_t stream)
{
    const float* x     = (const float*)d_in[0];
    const float* dw0   = (const float*)d_in[1];
    const float* dw1   = (const float*)d_in[2];
    const float* dw2   = (const float*)d_in[3];
    const float* pw0w  = (const float*)d_in[4];
    const float* pw0b  = (const float*)d_in[5];
    const float* pw1w  = (const float*)d_in[6];
    const float* pw1b  = (const float*)d_in[7];
    const float* pw2w  = (const float*)d_in[8];
    const float* pw2b  = (const float*)d_in[9];
    const float* rw1   = (const float*)d_in[10];
    const float* rb1   = (const float*)d_in[11];
    const float* rw2   = (const float*)d_in[12];
    const float* rb2   = (const float*)d_in[13];
    const float* t_raw = (const float*)d_in[14];

    float* ws      = (float*)d_ws;
    float* avgmap  = ws;                       // 524288 floats
    float* maxmap  = ws + 524288;              // 524288 floats
    float* partial = ws + 1048576;             // 1024 floats (512 blocks x 2)
    float* rw      = ws + 1049600;             // 96 floats

    float* Y  = (float*)d_out;
    float* sa = Y + (size_t)B_ * CHW_;         // 524288 floats

    k1_reduce<<<B_ * HW_ / 4 / 256, 256, 0, stream>>>(x, avgmap, maxmap, partial);
    k2_router<<<1, 64, 0, stream>>>(partial, rw1, rb1, rw2, rb2, rw);

    dim3 g34(H_ / 2, B_);
    k34_branches_apply<<<g34, 256, 0, stream>>>(
        x, avgmap, maxmap, dw0, dw1, dw2,
        pw0w, pw0b, pw1w, pw1b, pw2w, pw2b,
        rw, t_raw, Y, sa);
}